// Round 14
// baseline (409.087 us; speedup 1.0000x reference)
//
#include <hip/hip_runtime.h>

// ---------------------------------------------------------------------------
// hidden0 = zeros and the scan step is row-uniform => all T carry rows stay
// identical; everything reduces to ONE 256-dim recurrence
//     h_{t+1} = tanh(x_t @ W_ih + h_t @ W_hh),  out = (h_T @ fc_W + fc_b) bcast.
//
// R2-R4 evidence: weight non-residency (VGPR 52/80/100). Why reloads were
// legal: the per-step memory-clobber asm allows fresh per-iteration reloads;
// the allocator preferred that over 128+ resident regs. PINW closes the
// loophole: a value leaving asm("":"+v"(w)) cannot be recomputed by reload.
// Occupancy forced mechanically: 84 KB LDS pad -> 1 block/CU (16 waves,
// 4/SIMD) -> VGPR cap 128 >= ~100 needed; waves_per_eu(4,4) reinforces.
// Gates: VGPR_Count in [96,128], LDS_Block_Size ~88 KB.
// ---------------------------------------------------------------------------

#define T_LEN 512
#define H_DIM 256

typedef float f32x2 __attribute__((ext_vector_type(2)));
typedef float f32x4 __attribute__((ext_vector_type(4)));

__device__ __forceinline__ float fast_rcp(float x) {
    return __builtin_amdgcn_rcpf(x);
}
__device__ __forceinline__ float tanh_fast(float x) {
    float e = __expf(x + x);
    return 1.f - 2.f * fast_rcp(e + 1.f);
}
// butterfly-add over 8 lanes, pure DPP (VALU only, no LDS pipe):
// xor1 (quad_perm 0xB1), xor2 (quad_perm 0x4E), then row_half_mirror 0x141
// (lane i <-> 7-i within each 8; equals xor-4 after quad uniformity).
#define DPP_ADD(s, ctrl)                                                      \
    ((s) + __int_as_float(__builtin_amdgcn_mov_dpp(                           \
               __float_as_int(s), (ctrl), 0xF, 0xF, true)))
#define RED8(s)                                                               \
    do {                                                                      \
        s = DPP_ADD(s, 0xB1);                                                 \
        s = DPP_ADD(s, 0x4E);                                                 \
        s = DPP_ADD(s, 0x141);                                                \
    } while (0)

// ---------------------------------------------------------------------------
// Kernel A: V = x @ W_ih   (T x H). V aliases d_out (scratch).
// ---------------------------------------------------------------------------
__global__ __launch_bounds__(256) void vih_kernel(const float* __restrict__ x,
                                                  const float* __restrict__ W_ih,
                                                  float* __restrict__ V) {
    const int j  = threadIdx.x;
    const int t0 = blockIdx.x * 4;
    __shared__ float xs[4][H_DIM];
#pragma unroll
    for (int r = 0; r < 4; ++r) xs[r][j] = x[(t0 + r) * H_DIM + j];
    __syncthreads();
    float a0 = 0.f, a1 = 0.f, a2 = 0.f, a3 = 0.f;
#pragma unroll 8
    for (int i = 0; i < H_DIM; ++i) {
        float wv = W_ih[i * H_DIM + j];
        a0 = fmaf(xs[0][i], wv, a0);
        a1 = fmaf(xs[1][i], wv, a1);
        a2 = fmaf(xs[2][i], wv, a2);
        a3 = fmaf(xs[3][i], wv, a3);
    }
    V[(t0 + 0) * H_DIM + j] = a0;
    V[(t0 + 1) * H_DIM + j] = a1;
    V[(t0 + 2) * H_DIM + j] = a2;
    V[(t0 + 3) * H_DIM + j] = a3;
}

// ---------------------------------------------------------------------------
// Kernel B: recurrence. 1024 threads = 16 waves; 84 KB LDS pad => exactly
// 1 block/CU => 4 waves/SIMD => VGPR cap 128 >= ~100 needed. Thread
// (cg = tid>>3, g = tid&7): columns {2cg, 2cg+1}, rows g*32 .. g*32+31.
// Weights: 32 rows x 2 cols = 32 named f32x2 (row-pairs x col), pinned.
// h in LDS, slice stride 36 floats => 8 g-groups' ds_read_b128 land on bank
// quads {0,4,..,28}, 8-lane broadcast each: conflict-free. 8 b128/thread =
// 128 wave-instrs/CU/step. RED8 DPP reduce; g==0 writes ds_write_b64.
// One raw s_barrier/step, lgkmcnt(0) only (V prefetch keeps vmcnt in flight).
// ---------------------------------------------------------------------------
#define KLIST(X) X(0) X(1) X(2) X(3) X(4) X(5) X(6) X(7)

__global__ __attribute__((amdgpu_waves_per_eu(4, 4))) __launch_bounds__(1024)
void rnn_scan_kernel(const float* __restrict__ W_hh,
                     const float* V,
                     const float* __restrict__ fc_W,
                     const float* __restrict__ fc_b,
                     float* __restrict__ y_out) {
    const int tid = threadIdx.x;
    const int cg  = tid >> 3;    // column pair 0..127
    const int g   = tid & 7;     // row slice 0..7 (rows g*32 .. g*32+31)
    const int c0  = cg * 2;

    // Occupancy-forcing pad: 84 KB static LDS -> 1 block/CU (2x84 > 160 KB)
    // -> 16 waves = 4/SIMD -> register budget 128. Runtime guard prevents
    // folding; the store never executes (V holds vih output, never that NaN).
    __shared__ float lds_force[21504];
    if (__float_as_int(V[0]) == 0x7fc0dead)
        lds_force[tid] = V[1];

    // ---- weights: WA{k}_0 = rows (g*32+4k, +1) col c0; WA{k}_1 = rows
    // (+2,+3) col c0; WB{k}_* = same rows, col c0+1.
#define DECLW(k)                                                              \
    f32x2 WA##k##_0, WA##k##_1, WB##k##_0, WB##k##_1;
    KLIST(DECLW)
    {
        const float* wb = W_hh + (g * 32) * H_DIM + c0;
#define LOADW(k)                                                              \
    {                                                                         \
        const float* r0 = wb + (4 * (k) + 0) * H_DIM;                         \
        const float* r1 = wb + (4 * (k) + 1) * H_DIM;                         \
        const float* r2 = wb + (4 * (k) + 2) * H_DIM;                         \
        const float* r3 = wb + (4 * (k) + 3) * H_DIM;                         \
        WA##k##_0.x = r0[0]; WA##k##_0.y = r1[0];                             \
        WA##k##_1.x = r2[0]; WA##k##_1.y = r3[0];                             \
        WB##k##_0.x = r0[1]; WB##k##_0.y = r1[1];                             \
        WB##k##_1.x = r2[1]; WB##k##_1.y = r3[1];                             \
    }
        KLIST(LOADW)
    }
    // opaque pin: the pinned SSA value cannot be recomputed by re-loading
    // W_hh, so it must stay in registers (or visibly spill) across the loop.
#define PINW(k)                                                               \
    asm("" : "+v"(WA##k##_0), "+v"(WA##k##_1),                                \
             "+v"(WB##k##_0), "+v"(WB##k##_1));
    KLIST(PINW)

    // h: logical h[i] at float index (i>>5)*36 + (i&31); slice = 9 float4.
    __shared__ f32x4 h4p[2][72];
    {
        float* hz = (float*)h4p;
        for (int idx = tid; idx < 2 * 72 * 4; idx += 1024) hz[idx] = 0.f;
    }
    __syncthreads();

    const f32x2* Vp2 = (const f32x2*)V;        // V[t][c0,c0+1] = Vp2[t*128+cg]
    f32x2 vA = Vp2[0 * 128 + cg];
    f32x2 vB = Vp2[1 * 128 + cg];

#define CHUNK(k, hb)                                                          \
    {                                                                         \
        f32x4 hv = (hb)[k];                                                   \
        f32x2 lo; lo.x = hv.x; lo.y = hv.y;                                   \
        f32x2 hi; hi.x = hv.z; hi.y = hv.w;                                   \
        aA0 = __builtin_elementwise_fma(WA##k##_0, lo, aA0);                  \
        aA1 = __builtin_elementwise_fma(WA##k##_1, hi, aA1);                  \
        aB0 = __builtin_elementwise_fma(WB##k##_0, lo, aB0);                  \
        aB1 = __builtin_elementwise_fma(WB##k##_1, hi, aB1);                  \
    }

#define KLIST2(X, a) X(0, a) X(1, a) X(2, a) X(3, a)                          \
                     X(4, a) X(5, a) X(6, a) X(7, a)

#define RNN_STEP(vt, RB, WB_)                                                 \
    {                                                                         \
        const f32x4* hb = &h4p[RB][g * 9];                                    \
        f32x2 aA0 = {0.f, 0.f}, aA1 = {0.f, 0.f};                             \
        f32x2 aB0 = {0.f, 0.f}, aB1 = {0.f, 0.f};                             \
        KLIST2(CHUNK, hb)                                                     \
        f32x2 cAv = aA0 + aA1; float sA = cAv.x + cAv.y;                      \
        f32x2 cBv = aB0 + aB1; float sB = cBv.x + cBv.y;                      \
        RED8(sA); RED8(sB);                                                   \
        f32x2 hn;                                                             \
        hn.x = tanh_fast(sA + (vt).x);                                        \
        hn.y = tanh_fast(sB + (vt).y);                                        \
        if (g == 0)                                                           \
            *(f32x2*)((float*)h4p[WB_] + ((c0 >> 5) * 36 + (c0 & 31))) = hn;  \
        asm volatile("s_waitcnt lgkmcnt(0)" ::: "memory");                    \
        __builtin_amdgcn_s_barrier();                                         \
        asm volatile("" ::: "memory");                                        \
    }

    for (int t = 0; t < T_LEN; t += 2) {
        // prefetch v_{t+2}, v_{t+3}: raw barrier never drains vmcnt, so
        // these stay in flight under the next step's compute.
        f32x2 vA2 = Vp2[(t + 2 < T_LEN ? t + 2 : T_LEN - 1) * 128 + cg];
        f32x2 vB2 = Vp2[(t + 3 < T_LEN ? t + 3 : T_LEN - 1) * 128 + cg];
        RNN_STEP(vA, 0, 1);   // read buf0 -> write buf1
        RNN_STEP(vB, 1, 0);   // read buf1 -> write buf0
        vA = vA2;
        vB = vB2;
    }
    // T even => final h in buffer 0.

    // ---- tail: y[c] = sum_i h[i] * fc_W[i][c] + fc_b[c]  -> y_out (d_ws)
    {
        const f32x4* hb = &h4p[0][g * 9];
        const float* fp = fc_W + (g * 32) * H_DIM + c0;
        f32x2 aA0 = {0.f, 0.f}, aA1 = {0.f, 0.f};
        f32x2 aB0 = {0.f, 0.f}, aB1 = {0.f, 0.f};
#define FCCHUNK(k, hb)                                                        \
    {                                                                         \
        f32x4 hv = (hb)[k];                                                   \
        f32x2 lo; lo.x = hv.x; lo.y = hv.y;                                   \
        f32x2 hi; hi.x = hv.z; hi.y = hv.w;                                   \
        const float* r0 = fp + (4 * (k) + 0) * H_DIM;                         \
        const float* r1 = fp + (4 * (k) + 1) * H_DIM;                         \
        const float* r2 = fp + (4 * (k) + 2) * H_DIM;                         \
        const float* r3 = fp + (4 * (k) + 3) * H_DIM;                         \
        f32x2 fA0; fA0.x = r0[0]; fA0.y = r1[0];                              \
        f32x2 fA1; fA1.x = r2[0]; fA1.y = r3[0];                              \
        f32x2 fB0; fB0.x = r0[1]; fB0.y = r1[1];                              \
        f32x2 fB1; fB1.x = r2[1]; fB1.y = r3[1];                              \
        aA0 = __builtin_elementwise_fma(fA0, lo, aA0);                        \
        aA1 = __builtin_elementwise_fma(fA1, hi, aA1);                        \
        aB0 = __builtin_elementwise_fma(fB0, lo, aB0);                        \
        aB1 = __builtin_elementwise_fma(fB1, hi, aB1);                        \
    }
        KLIST2(FCCHUNK, hb)
        f32x2 cAv = aA0 + aA1; float sA = cAv.x + cAv.y;
        f32x2 cBv = aB0 + aB1; float sB = cBv.x + cBv.y;
        RED8(sA); RED8(sB);
        if (g == 0) {
            f32x2 yv;
            yv.x = sA + fc_b[c0 + 0];
            yv.y = sB + fc_b[c0 + 1];
            ((f32x2*)y_out)[cg] = yv;
        }
    }
}

// ---------------------------------------------------------------------------
// Kernel C: broadcast y (256 floats in d_ws) to all T rows of out (many CUs).
// ---------------------------------------------------------------------------
__global__ __launch_bounds__(256) void bcast_kernel(const float* __restrict__ y,
                                                    float* __restrict__ out) {
    __shared__ f32x4 yl[H_DIM / 4];
    if (threadIdx.x < H_DIM / 4) yl[threadIdx.x] = ((const f32x4*)y)[threadIdx.x];
    __syncthreads();
    const int base = blockIdx.x * (4 * H_DIM / 4);
    f32x4* o4 = (f32x4*)out;
    o4[base + threadIdx.x] = yl[threadIdx.x & 63];
}

extern "C" void kernel_launch(void* const* d_in, const int* in_sizes, int n_in,
                              void* d_out, int out_size, void* d_ws, size_t ws_size,
                              hipStream_t stream) {
    (void)in_sizes; (void)n_in; (void)ws_size; (void)out_size;
    const float* x    = (const float*)d_in[0];
    const float* W_ih = (const float*)d_in[1];
    const float* W_hh = (const float*)d_in[2];
    const float* fc_W = (const float*)d_in[3];
    const float* fc_b = (const float*)d_in[4];
    float* out = (float*)d_out;
    float* y   = (float*)d_ws;

    // d_out doubles as scratch for V = x @ W_ih (read-only in the scan;
    // bcast overwrites d_out last).
    float* V = out;

    vih_kernel<<<T_LEN / 4, 256, 0, stream>>>(x, W_ih, V);
    rnn_scan_kernel<<<1, 1024, 0, stream>>>(W_hh, V, fc_W, fc_b, y);
    bcast_kernel<<<T_LEN / 4, 256, 0, stream>>>(y, out);
}

// Round 15
// 407.849 us; speedup vs baseline: 1.0030x; 1.0030x over previous
//
#include <hip/hip_runtime.h>

// ---------------------------------------------------------------------------
// hidden0 = zeros and the scan step is row-uniform => all T carry rows stay
// identical; everything reduces to ONE 256-dim recurrence
//     h_{t+1} = tanh(x_t @ W_ih + h_t @ W_hh),  out = (h_T @ fc_W + fc_b) bcast.
//
// R14 post-mortem: LDS_Block_Size=2560 proved the 84 KB pad was DCE'd (store
// never read -> dead -> array gone); occupancy calc saw 2.5 KB -> allocator
// targeted 8 waves/SIMD (cap 64) -> weights spilled (VGPR=52, 342us).
// waves_per_eu(4,4) alone was NOT honored. Fix: VOLATILE pad + one
// unconditional volatile store/thread -- cannot be eliminated, mechanically
// forces 1 block/CU (16 waves, 4/SIMD) -> pressure target 128 >= ~100 needed.
// Gates: LDS_Block_Size ~88 KB (pad survived), VGPR_Count >= ~100.
// ---------------------------------------------------------------------------

#define T_LEN 512
#define H_DIM 256

typedef float f32x2 __attribute__((ext_vector_type(2)));
typedef float f32x4 __attribute__((ext_vector_type(4)));

__device__ __forceinline__ float fast_rcp(float x) {
    return __builtin_amdgcn_rcpf(x);
}
__device__ __forceinline__ float tanh_fast(float x) {
    float e = __expf(x + x);
    return 1.f - 2.f * fast_rcp(e + 1.f);
}
// butterfly-add over 8 lanes, pure DPP (VALU only, no LDS pipe):
// xor1 (quad_perm 0xB1), xor2 (quad_perm 0x4E), then row_half_mirror 0x141
// (lane i <-> 7-i within each 8; equals xor-4 after quad uniformity).
#define DPP_ADD(s, ctrl)                                                      \
    ((s) + __int_as_float(__builtin_amdgcn_mov_dpp(                           \
               __float_as_int(s), (ctrl), 0xF, 0xF, true)))
#define RED8(s)                                                               \
    do {                                                                      \
        s = DPP_ADD(s, 0xB1);                                                 \
        s = DPP_ADD(s, 0x4E);                                                 \
        s = DPP_ADD(s, 0x141);                                                \
    } while (0)

// ---------------------------------------------------------------------------
// Kernel A: V = x @ W_ih   (T x H). V aliases d_out (scratch).
// ---------------------------------------------------------------------------
__global__ __launch_bounds__(256) void vih_kernel(const float* __restrict__ x,
                                                  const float* __restrict__ W_ih,
                                                  float* __restrict__ V) {
    const int j  = threadIdx.x;
    const int t0 = blockIdx.x * 4;
    __shared__ float xs[4][H_DIM];
#pragma unroll
    for (int r = 0; r < 4; ++r) xs[r][j] = x[(t0 + r) * H_DIM + j];
    __syncthreads();
    float a0 = 0.f, a1 = 0.f, a2 = 0.f, a3 = 0.f;
#pragma unroll 8
    for (int i = 0; i < H_DIM; ++i) {
        float wv = W_ih[i * H_DIM + j];
        a0 = fmaf(xs[0][i], wv, a0);
        a1 = fmaf(xs[1][i], wv, a1);
        a2 = fmaf(xs[2][i], wv, a2);
        a3 = fmaf(xs[3][i], wv, a3);
    }
    V[(t0 + 0) * H_DIM + j] = a0;
    V[(t0 + 1) * H_DIM + j] = a1;
    V[(t0 + 2) * H_DIM + j] = a2;
    V[(t0 + 3) * H_DIM + j] = a3;
}

// ---------------------------------------------------------------------------
// Kernel B: recurrence. 1024 threads = 16 waves; 84 KB VOLATILE LDS pad =>
// exactly 1 block/CU => 4 waves/SIMD => VGPR cap 128 >= ~100 needed. Thread
// (cg = tid>>3, g = tid&7): columns {2cg, 2cg+1}, rows g*32 .. g*32+31.
// Weights: 32 rows x 2 cols = 32 named f32x2 (row-pairs x col), pinned.
// h in LDS, slice stride 36 floats => 8 g-groups' ds_read_b128 land on bank
// quads {0,4,..,28}, 8-lane broadcast each: conflict-free. 8 b128/thread =
// 128 wave-instrs/CU/step. RED8 DPP reduce; g==0 writes ds_write_b64.
// One raw s_barrier/step, lgkmcnt(0) only (V prefetch keeps vmcnt in flight).
// ---------------------------------------------------------------------------
#define KLIST(X) X(0) X(1) X(2) X(3) X(4) X(5) X(6) X(7)

__global__ __attribute__((amdgpu_waves_per_eu(4, 4))) __launch_bounds__(1024)
void rnn_scan_kernel(const float* __restrict__ W_hh,
                     const float* V,
                     const float* __restrict__ fc_W,
                     const float* __restrict__ fc_b,
                     float* __restrict__ y_out) {
    const int tid = threadIdx.x;
    const int cg  = tid >> 3;    // column pair 0..127
    const int g   = tid & 7;     // row slice 0..7 (rows g*32 .. g*32+31)
    const int c0  = cg * 2;

    // Occupancy-forcing pad: 84 KB VOLATILE LDS. The volatile store below is
    // side-effecting and cannot be DCE'd (R14: non-volatile version was
    // eliminated because it was never read). 84 KB -> 1 block/CU -> 16 waves
    // = 4/SIMD -> register pressure target 128.
    volatile __shared__ float lds_force[21504];
    lds_force[tid] = 0.f;   // one conflict-free ds_write_b32, once per kernel

    // ---- weights: WA{k}_0 = rows (g*32+4k, +1) col c0; WA{k}_1 = rows
    // (+2,+3) col c0; WB{k}_* = same rows, col c0+1.
#define DECLW(k)                                                              \
    f32x2 WA##k##_0, WA##k##_1, WB##k##_0, WB##k##_1;
    KLIST(DECLW)
    {
        const float* wb = W_hh + (g * 32) * H_DIM + c0;
#define LOADW(k)                                                              \
    {                                                                         \
        const float* r0 = wb + (4 * (k) + 0) * H_DIM;                         \
        const float* r1 = wb + (4 * (k) + 1) * H_DIM;                         \
        const float* r2 = wb + (4 * (k) + 2) * H_DIM;                         \
        const float* r3 = wb + (4 * (k) + 3) * H_DIM;                         \
        WA##k##_0.x = r0[0]; WA##k##_0.y = r1[0];                             \
        WA##k##_1.x = r2[0]; WA##k##_1.y = r3[0];                             \
        WB##k##_0.x = r0[1]; WB##k##_0.y = r1[1];                             \
        WB##k##_1.x = r2[1]; WB##k##_1.y = r3[1];                             \
    }
        KLIST(LOADW)
    }
    // opaque pin: the pinned SSA value cannot be recomputed by re-loading
    // W_hh, so it must stay in registers (or visibly spill) across the loop.
#define PINW(k)                                                               \
    asm("" : "+v"(WA##k##_0), "+v"(WA##k##_1),                                \
             "+v"(WB##k##_0), "+v"(WB##k##_1));
    KLIST(PINW)

    // h: logical h[i] at float index (i>>5)*36 + (i&31); slice = 9 float4.
    __shared__ f32x4 h4p[2][72];
    {
        float* hz = (float*)h4p;
        for (int idx = tid; idx < 2 * 72 * 4; idx += 1024) hz[idx] = 0.f;
    }
    __syncthreads();

    const f32x2* Vp2 = (const f32x2*)V;        // V[t][c0,c0+1] = Vp2[t*128+cg]
    f32x2 vA = Vp2[0 * 128 + cg];
    f32x2 vB = Vp2[1 * 128 + cg];

#define CHUNK(k, hb)                                                          \
    {                                                                         \
        f32x4 hv = (hb)[k];                                                   \
        f32x2 lo; lo.x = hv.x; lo.y = hv.y;                                   \
        f32x2 hi; hi.x = hv.z; hi.y = hv.w;                                   \
        aA0 = __builtin_elementwise_fma(WA##k##_0, lo, aA0);                  \
        aA1 = __builtin_elementwise_fma(WA##k##_1, hi, aA1);                  \
        aB0 = __builtin_elementwise_fma(WB##k##_0, lo, aB0);                  \
        aB1 = __builtin_elementwise_fma(WB##k##_1, hi, aB1);                  \
    }

#define KLIST2(X, a) X(0, a) X(1, a) X(2, a) X(3, a)                          \
                     X(4, a) X(5, a) X(6, a) X(7, a)

#define RNN_STEP(vt, RB, WB_)                                                 \
    {                                                                         \
        const f32x4* hb = &h4p[RB][g * 9];                                    \
        f32x2 aA0 = {0.f, 0.f}, aA1 = {0.f, 0.f};                             \
        f32x2 aB0 = {0.f, 0.f}, aB1 = {0.f, 0.f};                             \
        KLIST2(CHUNK, hb)                                                     \
        f32x2 cAv = aA0 + aA1; float sA = cAv.x + cAv.y;                      \
        f32x2 cBv = aB0 + aB1; float sB = cBv.x + cBv.y;                      \
        RED8(sA); RED8(sB);                                                   \
        f32x2 hn;                                                             \
        hn.x = tanh_fast(sA + (vt).x);                                        \
        hn.y = tanh_fast(sB + (vt).y);                                        \
        if (g == 0)                                                           \
            *(f32x2*)((float*)h4p[WB_] + ((c0 >> 5) * 36 + (c0 & 31))) = hn;  \
        asm volatile("s_waitcnt lgkmcnt(0)" ::: "memory");                    \
        __builtin_amdgcn_s_barrier();                                         \
        asm volatile("" ::: "memory");                                        \
    }

    for (int t = 0; t < T_LEN; t += 2) {
        // prefetch v_{t+2}, v_{t+3}: raw barrier never drains vmcnt, so
        // these stay in flight under the next step's compute.
        f32x2 vA2 = Vp2[(t + 2 < T_LEN ? t + 2 : T_LEN - 1) * 128 + cg];
        f32x2 vB2 = Vp2[(t + 3 < T_LEN ? t + 3 : T_LEN - 1) * 128 + cg];
        RNN_STEP(vA, 0, 1);   // read buf0 -> write buf1
        RNN_STEP(vB, 1, 0);   // read buf1 -> write buf0
        vA = vA2;
        vB = vB2;
    }
    // T even => final h in buffer 0.

    // ---- tail: y[c] = sum_i h[i] * fc_W[i][c] + fc_b[c]  -> y_out (d_ws)
    {
        const f32x4* hb = &h4p[0][g * 9];
        const float* fp = fc_W + (g * 32) * H_DIM + c0;
        f32x2 aA0 = {0.f, 0.f}, aA1 = {0.f, 0.f};
        f32x2 aB0 = {0.f, 0.f}, aB1 = {0.f, 0.f};
#define FCCHUNK(k, hb)                                                        \
    {                                                                         \
        f32x4 hv = (hb)[k];                                                   \
        f32x2 lo; lo.x = hv.x; lo.y = hv.y;                                   \
        f32x2 hi; hi.x = hv.z; hi.y = hv.w;                                   \
        const float* r0 = fp + (4 * (k) + 0) * H_DIM;                         \
        const float* r1 = fp + (4 * (k) + 1) * H_DIM;                         \
        const float* r2 = fp + (4 * (k) + 2) * H_DIM;                         \
        const float* r3 = fp + (4 * (k) + 3) * H_DIM;                         \
        f32x2 fA0; fA0.x = r0[0]; fA0.y = r1[0];                              \
        f32x2 fA1; fA1.x = r2[0]; fA1.y = r3[0];                              \
        f32x2 fB0; fB0.x = r0[1]; fB0.y = r1[1];                              \
        f32x2 fB1; fB1.x = r2[1]; fB1.y = r3[1];                              \
        aA0 = __builtin_elementwise_fma(fA0, lo, aA0);                        \
        aA1 = __builtin_elementwise_fma(fA1, hi, aA1);                        \
        aB0 = __builtin_elementwise_fma(fB0, lo, aB0);                        \
        aB1 = __builtin_elementwise_fma(fB1, hi, aB1);                        \
    }
        KLIST2(FCCHUNK, hb)
        f32x2 cAv = aA0 + aA1; float sA = cAv.x + cAv.y;
        f32x2 cBv = aB0 + aB1; float sB = cBv.x + cBv.y;
        RED8(sA); RED8(sB);
        if (g == 0) {
            f32x2 yv;
            yv.x = sA + fc_b[c0 + 0];
            yv.y = sB + fc_b[c0 + 1];
            ((f32x2*)y_out)[cg] = yv;
        }
    }
}

// ---------------------------------------------------------------------------
// Kernel C: broadcast y (256 floats in d_ws) to all T rows of out (many CUs).
// ---------------------------------------------------------------------------
__global__ __launch_bounds__(256) void bcast_kernel(const float* __restrict__ y,
                                                    float* __restrict__ out) {
    __shared__ f32x4 yl[H_DIM / 4];
    if (threadIdx.x < H_DIM / 4) yl[threadIdx.x] = ((const f32x4*)y)[threadIdx.x];
    __syncthreads();
    const int base = blockIdx.x * (4 * H_DIM / 4);
    f32x4* o4 = (f32x4*)out;
    o4[base + threadIdx.x] = yl[threadIdx.x & 63];
}

extern "C" void kernel_launch(void* const* d_in, const int* in_sizes, int n_in,
                              void* d_out, int out_size, void* d_ws, size_t ws_size,
                              hipStream_t stream) {
    (void)in_sizes; (void)n_in; (void)ws_size; (void)out_size;
    const float* x    = (const float*)d_in[0];
    const float* W_ih = (const float*)d_in[1];
    const float* W_hh = (const float*)d_in[2];
    const float* fc_W = (const float*)d_in[3];
    const float* fc_b = (const float*)d_in[4];
    float* out = (float*)d_out;
    float* y   = (float*)d_ws;

    // d_out doubles as scratch for V = x @ W_ih (read-only in the scan;
    // bcast overwrites d_out last).
    float* V = out;

    vih_kernel<<<T_LEN / 4, 256, 0, stream>>>(x, W_ih, V);
    rnn_scan_kernel<<<1, 1024, 0, stream>>>(W_hh, V, fc_W, fc_b, y);
    bcast_kernel<<<T_LEN / 4, 256, 0, stream>>>(y, out);
}